// Round 4
// baseline (2312.762 us; speedup 1.0000x reference)
//
#include <hip/hip_runtime.h>

// LSTM feedback net: B=16384, T=48 warmup, F=4, UNITS=256, 24 AR steps.
// R4: 512-thr blocks (2 waves/SIMD, 256-reg budget -> no spill), wave owns
// 32 units (2 n-tiles per gate), c back in registers, h dbuf in LDS (74 KB).
// Software-pipelined: wa(kt+1) global prefetch + hb(kt+1) LDS prefetch
// overlap kt's MFMAs. Raw `s_waitcnt lgkmcnt(0); s_barrier` instead of
// __syncthreads() so weight loads stay in flight across the barrier
// (compiler's __syncthreads drains vmcnt(0) -> kills cross-phase prefetch).

typedef unsigned short u16;
typedef __attribute__((ext_vector_type(8))) short bf16x8;
typedef __attribute__((ext_vector_type(4))) float f32x4;

#define PITCH 296    // hext row pitch, elems (592 B/row, 16B-aligned)
#define HB 18944     // elems per h buffer (64*296)
#define WARM 48
#define STEPS 71     // 48 warmup + 23 AR cell steps

__device__ __forceinline__ u16 f2bf(float f) {
    unsigned u = __float_as_uint(f);
    u += 0x7FFFu + ((u >> 16) & 1u);   // round-to-nearest-even
    return (u16)(u >> 16);
}

__device__ __forceinline__ float sigm(float x) {
    return __builtin_amdgcn_rcpf(1.0f + __expf(-x));
}
// tanh(x) = 2*sigmoid(2x)-1 ; saturates correctly without NaN
__device__ __forceinline__ float tanh_f(float x) {
    return __builtin_amdgcn_rcpf(1.0f + __expf(-2.0f * x)) * 2.0f - 1.0f;
}

// LDS-only barrier: drain LDS ops, do NOT drain vmcnt (global loads/stores
// stay in flight across it). All global data here is read-only or write-only.
__device__ __forceinline__ void sync_lds() {
    asm volatile("s_waitcnt lgkmcnt(0)\n\ts_barrier" ::: "memory");
}

// ---- prep (unchanged): pack Whext (K=288 x N=1024) and Wdext into fragment
// blocks; lane l of block (kt,nt) holds W[kt*32+(l>>4)*8+j][nt*16+(l&15)].
// Fed as operand A: A[m=unit][k]. K rows: 0..255 Wh/Wd, 256..259 Wx, 260 bias.
__global__ void prep_weights(const float* __restrict__ Wx,
                             const float* __restrict__ Wh,
                             const float* __restrict__ b,
                             const float* __restrict__ Wd,
                             const float* __restrict__ bd,
                             u16* __restrict__ whext,
                             u16* __restrict__ wdp) {
    int idx = blockIdx.x * 256 + threadIdx.x;   // one thread per 16B chunk
    if (idx < 36864) {                          // 9 kt * 64 nt * 64 lanes
        int lane = idx & 63;
        int blk = idx >> 6;
        int nt = blk & 63;
        int kt = blk >> 6;
        int kbase = kt * 32 + (lane >> 4) * 8;
        int n = nt * 16 + (lane & 15);
        u16 v[8];
#pragma unroll
        for (int j = 0; j < 8; ++j) {
            int k = kbase + j;
            float f = 0.0f;
            if (k < 256) f = Wh[k * 1024 + n];
            else if (k < 260) f = Wx[(k - 256) * 1024 + n];
            else if (k == 260) f = b[n];
            v[j] = f2bf(f);
        }
        ushort4* dst = (ushort4*)(whext + (size_t)idx * 8);
        dst[0] = make_ushort4(v[0], v[1], v[2], v[3]);
        dst[1] = make_ushort4(v[4], v[5], v[6], v[7]);
    } else if (idx < 36864 + 576) {             // Wdext: 9 kt * 64 lanes
        int id2 = idx - 36864;
        int lane = id2 & 63;
        int kt = id2 >> 6;
        int kbase = kt * 32 + (lane >> 4) * 8;
        int n = lane & 15;
        u16 v[8];
#pragma unroll
        for (int j = 0; j < 8; ++j) {
            int k = kbase + j;
            float f = 0.0f;
            if (n < 4) {
                if (k < 256) f = Wd[k * 4 + n];
                else if (k == 260) f = bd[n];
            }
            v[j] = f2bf(f);
        }
        ushort4* dst = (ushort4*)(wdp + (size_t)id2 * 8);
        dst[0] = make_ushort4(v[0], v[1], v[2], v[3]);
        dst[1] = make_ushort4(v[4], v[5], v[6], v[7]);
    }
}

__global__ __launch_bounds__(512, 2) void lstm_main(
    const float* __restrict__ x, const u16* __restrict__ whext,
    const u16* __restrict__ wdp, float* __restrict__ out) {
    __shared__ __align__(16) u16 hbuf[2 * HB];   // h double buffer, bf16

    const int tid = threadIdx.x;
    const int w = tid >> 6;        // wave 0..7 -> units [32w, 32w+32)
    const int l = tid & 63;
    const int col = l & 15;        // batch col within tile
    const int quad = l >> 4;
    const long long rowBase = (long long)blockIdx.x * 64;

    {   // zero both h buffers (incl. K-pad cols 261..287)
        int4 z = make_int4(0, 0, 0, 0);
        for (int i = tid; i < 4736; i += 512) ((int4*)hbuf)[i] = z;
    }
    sync_lds();
    if (tid < 64) {
        // constant-1 column (k=260) feeding the bias row, in BOTH buffers
        hbuf[tid * PITCH + 260] = (u16)0x3F80;
        hbuf[HB + tid * PITCH + 260] = (u16)0x3F80;
        // x_0 -> buffer 0, cols 256..259
        const float4 xv = *(const float4*)(x + (rowBase + tid) * 192);
        u16* p = &hbuf[tid * PITCH + 256];
        p[0] = f2bf(xv.x); p[1] = f2bf(xv.y); p[2] = f2bf(xv.z); p[3] = f2bf(xv.w);
    }

    f32x4 c[4][2];     // cell state: [bt][nh]; unit = 32w+16nh+4quad+r, batch 16bt+col
#pragma unroll
    for (int bt = 0; bt < 4; ++bt)
#pragma unroll
        for (int nh = 0; nh < 2; ++nh) c[bt][nh] = (f32x4){0.f, 0.f, 0.f, 0.f};

    const char* __restrict__ wp = (const char*)whext;
    const bf16x8* __restrict__ dfrag = (const bf16x8*)wdp;
    // per-lane byte offsets into whext for (g, nh): frag (kt, nt=16g+2w+nh)
    int voff[4][2];
#pragma unroll
    for (int g = 0; g < 4; ++g)
#pragma unroll
        for (int nh = 0; nh < 2; ++nh)
            voff[g][nh] = ((16 * g + 2 * w + nh) * 64 + l) * 16;

    for (int step = 0; step < STEPS; ++step) {
        const u16* hr = hbuf + (step & 1) * HB;      // read buffer
        u16* hw = hbuf + ((step & 1) ^ 1) * HB;      // write buffer

        // issue kt=0 weight loads BEFORE the barrier (global, no LDS hazard)
        bf16x8 wa[2][4][2];
#pragma unroll
        for (int g = 0; g < 4; ++g)
#pragma unroll
            for (int nh = 0; nh < 2; ++nh)
                wa[0][g][nh] = *(const bf16x8*)(wp + voff[g][nh]);

        sync_lds();   // h/x/bias of hr ready; prior reads of hw done

        f32x4 acc[4][4][2];   // [bt][g][nh]
#pragma unroll
        for (int bt = 0; bt < 4; ++bt)
#pragma unroll
            for (int g = 0; g < 4; ++g)
#pragma unroll
                for (int nh = 0; nh < 2; ++nh) acc[bt][g][nh] = (f32x4){0.f, 0.f, 0.f, 0.f};

        bf16x8 hb[2][4];
#pragma unroll
        for (int bt = 0; bt < 4; ++bt)
            hb[0][bt] = *(const bf16x8*)&hr[(16 * bt + col) * PITCH + quad * 8];

#pragma unroll
        for (int kt = 0; kt < 9; ++kt) {
            const int cur = kt & 1, nxt = cur ^ 1;
            if (kt < 8) {   // prefetch kt+1: LDS h-frags + global weight frags
#pragma unroll
                for (int bt = 0; bt < 4; ++bt)
                    hb[nxt][bt] = *(const bf16x8*)&hr[(16 * bt + col) * PITCH + (kt + 1) * 32 + quad * 8];
#pragma unroll
                for (int g = 0; g < 4; ++g)
#pragma unroll
                    for (int nh = 0; nh < 2; ++nh)
                        wa[nxt][g][nh] = *(const bf16x8*)(wp + (kt + 1) * 65536 + voff[g][nh]);
            }
#pragma unroll
            for (int g = 0; g < 4; ++g)
#pragma unroll
                for (int nh = 0; nh < 2; ++nh)
#pragma unroll
                    for (int bt = 0; bt < 4; ++bt)
                        acc[bt][g][nh] = __builtin_amdgcn_mfma_f32_16x16x32_bf16(
                            wa[cur][g][nh], hb[cur][bt], acc[bt][g][nh], 0, 0, 0);
        }

        // gates; lane holds units u = 32w+16nh+4quad+r, batch m = 16bt+col
#pragma unroll
        for (int bt = 0; bt < 4; ++bt)
#pragma unroll
            for (int nh = 0; nh < 2; ++nh) {
                f32x4 cold = c[bt][nh];
                f32x4 cnew;
                u16 hh[4];
#pragma unroll
                for (int r = 0; r < 4; ++r) {
                    float iv = sigm(acc[bt][0][nh][r]);
                    float fv = sigm(acc[bt][1][nh][r]);
                    float gv = tanh_f(acc[bt][2][nh][r]);
                    float ov = sigm(acc[bt][3][nh][r]);
                    float cn = fv * cold[r] + iv * gv;
                    cnew[r] = cn;
                    hh[r] = f2bf(ov * tanh_f(cn));
                }
                c[bt][nh] = cnew;
                *(ushort4*)&hw[(16 * bt + col) * PITCH + 32 * w + 16 * nh + 4 * quad] =
                    make_ushort4(hh[0], hh[1], hh[2], hh[3]);
            }

        if (step < WARM - 1) {
            if (w == 0) {   // x_{step+1} -> write buffer (read next step)
                const float4 xv = *(const float4*)(x + (rowBase + l) * 192 + (step + 1) * 4);
                u16* p = &hw[l * PITCH + 256];
                p[0] = f2bf(xv.x); p[1] = f2bf(xv.y); p[2] = f2bf(xv.z); p[3] = f2bf(xv.w);
            }
        } else {
            sync_lds();        // h_new in hw visible for pred GEMM
            if (w < 4) {       // pred^T = Wdext^T @ h_new^T ; wave w -> batch-tile w
                f32x4 pacc = (f32x4){0.f, 0.f, 0.f, 0.f};
#pragma unroll
                for (int kt = 0; kt < 9; ++kt) {
                    bf16x8 hbp = *(const bf16x8*)&hw[(16 * w + col) * PITCH + kt * 32 + quad * 8];
                    bf16x8 wap = dfrag[kt * 64 + l];
                    pacc = __builtin_amdgcn_mfma_f32_16x16x32_bf16(wap, hbp, pacc, 0, 0, 0);
                }
                if (quad == 0) {   // D rows 0..3 = the 4 features of batch 16w+col
                    int s = step - (WARM - 1);
                    *(float4*)&out[((rowBase + 16 * w + col) * 24 + s) * 4] =
                        make_float4(pacc[0], pacc[1], pacc[2], pacc[3]);
                    // feed back as next x_t
                    *(ushort4*)&hw[(16 * w + col) * PITCH + 256] =
                        make_ushort4(f2bf(pacc[0]), f2bf(pacc[1]), f2bf(pacc[2]), f2bf(pacc[3]));
                }
            }
        }
    }
}

extern "C" void kernel_launch(void* const* d_in, const int* in_sizes, int n_in,
                              void* d_out, int out_size, void* d_ws, size_t ws_size,
                              hipStream_t stream) {
    const float* x  = (const float*)d_in[0];   // [16384,48,4]
    const float* Wx = (const float*)d_in[1];   // [4,1024]
    const float* Wh = (const float*)d_in[2];   // [256,1024]
    const float* b  = (const float*)d_in[3];   // [1024]
    const float* Wd = (const float*)d_in[4];   // [256,4]
    const float* bd = (const float*)d_in[5];   // [4]
    float* out = (float*)d_out;                // [16384,24,4] fp32

    u16* whext = (u16*)d_ws;                        // 589824 B
    u16* wdp = (u16*)((char*)d_ws + 36864 * 16);    // 9216 B

    prep_weights<<<(36864 + 576 + 255) / 256, 256, 0, stream>>>(Wx, Wh, b, Wd, bd, whext, wdp);
    lstm_main<<<256, 512, 0, stream>>>(x, whext, wdp, out);
}

// Round 5
// 837.819 us; speedup vs baseline: 2.7605x; 2.7605x over previous
//
#include <hip/hip_runtime.h>

// LSTM feedback net: B=16384, T=48 warmup, F=4, UNITS=256, 24 AR steps.
// R5: fit 256 regs/wave exactly. 512-thr blocks (8 waves, 2/SIMD).
//  - acc 128 (AGPR) + waA/waB 64 + hbA/hbB 32 + voff 8 + misc ~12 = ~244.
//  - c state in LDS (R3 showed this is ~free; saves 32 regs).
//  - kt-loop: explicit A/B rotation, #pragma unroll 1 -> compiler cannot
//    hoist >1 kt of weight loads (full unroll caused the R1/R3/R4 spills).
//  - LDS-only barrier (s_waitcnt lgkmcnt(0); s_barrier): kt=0 weight loads
//    issued pre-barrier stay in flight across it.

typedef unsigned short u16;
typedef __attribute__((ext_vector_type(8))) short bf16x8;
typedef __attribute__((ext_vector_type(4))) float f32x4;

#define PITCH 296    // hext row pitch, elems (592 B/row; bank stride 20 -> ~2-way, free)
#define HB 18944     // elems per h buffer (64*296)
#define CPITCH 264   // c row pitch, floats (1056 B; 4-way on b128, minor)
#define WARM 48
#define STEPS 71     // 48 warmup + 23 AR cell steps

__device__ __forceinline__ u16 f2bf(float f) {
    unsigned u = __float_as_uint(f);
    u += 0x7FFFu + ((u >> 16) & 1u);   // round-to-nearest-even
    return (u16)(u >> 16);
}

__device__ __forceinline__ float sigm(float x) {
    return __builtin_amdgcn_rcpf(1.0f + __expf(-x));
}
// tanh(x) = 2*sigmoid(2x)-1 ; saturates correctly without NaN
__device__ __forceinline__ float tanh_f(float x) {
    return __builtin_amdgcn_rcpf(1.0f + __expf(-2.0f * x)) * 2.0f - 1.0f;
}

// LDS-only barrier: drain LDS ops, NOT vmcnt -> global loads stay in flight.
__device__ __forceinline__ void sync_lds() {
    asm volatile("s_waitcnt lgkmcnt(0)\n\ts_barrier" ::: "memory");
}

// ---- prep (unchanged): pack Whext (K=288 x N=1024) and Wdext into fragment
// blocks; lane l of block (kt,nt) holds W[kt*32+(l>>4)*8+j][nt*16+(l&15)].
// Fed as operand A: A[m=unit][k]. K rows: 0..255 Wh/Wd, 256..259 Wx, 260 bias.
__global__ void prep_weights(const float* __restrict__ Wx,
                             const float* __restrict__ Wh,
                             const float* __restrict__ b,
                             const float* __restrict__ Wd,
                             const float* __restrict__ bd,
                             u16* __restrict__ whext,
                             u16* __restrict__ wdp) {
    int idx = blockIdx.x * 256 + threadIdx.x;   // one thread per 16B chunk
    if (idx < 36864) {                          // 9 kt * 64 nt * 64 lanes
        int lane = idx & 63;
        int blk = idx >> 6;
        int nt = blk & 63;
        int kt = blk >> 6;
        int kbase = kt * 32 + (lane >> 4) * 8;
        int n = nt * 16 + (lane & 15);
        u16 v[8];
#pragma unroll
        for (int j = 0; j < 8; ++j) {
            int k = kbase + j;
            float f = 0.0f;
            if (k < 256) f = Wh[k * 1024 + n];
            else if (k < 260) f = Wx[(k - 256) * 1024 + n];
            else if (k == 260) f = b[n];
            v[j] = f2bf(f);
        }
        ushort4* dst = (ushort4*)(whext + (size_t)idx * 8);
        dst[0] = make_ushort4(v[0], v[1], v[2], v[3]);
        dst[1] = make_ushort4(v[4], v[5], v[6], v[7]);
    } else if (idx < 36864 + 576) {             // Wdext: 9 kt * 64 lanes
        int id2 = idx - 36864;
        int lane = id2 & 63;
        int kt = id2 >> 6;
        int kbase = kt * 32 + (lane >> 4) * 8;
        int n = lane & 15;
        u16 v[8];
#pragma unroll
        for (int j = 0; j < 8; ++j) {
            int k = kbase + j;
            float f = 0.0f;
            if (n < 4) {
                if (k < 256) f = Wd[k * 4 + n];
                else if (k == 260) f = bd[n];
            }
            v[j] = f2bf(f);
        }
        ushort4* dst = (ushort4*)(wdp + (size_t)id2 * 8);
        dst[0] = make_ushort4(v[0], v[1], v[2], v[3]);
        dst[1] = make_ushort4(v[4], v[5], v[6], v[7]);
    }
}

#define MFMA_BURST(WA, HBX)                                                   \
    _Pragma("unroll") for (int g = 0; g < 4; ++g)                             \
    _Pragma("unroll") for (int nh = 0; nh < 2; ++nh)                          \
    _Pragma("unroll") for (int bt = 0; bt < 4; ++bt)                          \
        acc[bt][g][nh] = __builtin_amdgcn_mfma_f32_16x16x32_bf16(             \
            WA[g][nh], HBX[bt], acc[bt][g][nh], 0, 0, 0);

__global__ __launch_bounds__(512, 2) void lstm_main(
    const float* __restrict__ x, const u16* __restrict__ whext,
    const u16* __restrict__ wdp, float* __restrict__ out) {
    __shared__ __align__(16) unsigned char smem[143360];
    u16* hbuf = (u16*)smem;                    // 2 x 18944 elems bf16 (75776 B)
    float* cbuf = (float*)(smem + 75776);      // c: [batch 64][unit, pitch 264] fp32

    const int tid = threadIdx.x;
    const int w = tid >> 6;        // wave 0..7 -> units [32w, 32w+32)
    const int l = tid & 63;
    const int col = l & 15;        // batch col within tile
    const int quad = l >> 4;
    const long long rowBase = (long long)blockIdx.x * 64;

    {   // zero all LDS (h buffers incl. pad cols, c)
        int4 z = make_int4(0, 0, 0, 0);
        for (int i = tid; i < 8960; i += 512) ((int4*)smem)[i] = z;
    }
    sync_lds();
    if (tid < 64) {
        hbuf[tid * PITCH + 260] = (u16)0x3F80;        // bias-1 col, buffer 0
        hbuf[HB + tid * PITCH + 260] = (u16)0x3F80;   // and buffer 1
        const float4 xv = *(const float4*)(x + (rowBase + tid) * 192);
        u16* p = &hbuf[tid * PITCH + 256];             // x_0 -> buffer 0
        p[0] = f2bf(xv.x); p[1] = f2bf(xv.y); p[2] = f2bf(xv.z); p[3] = f2bf(xv.w);
    }

    const char* __restrict__ wp = (const char*)whext;
    const bf16x8* __restrict__ dfrag = (const bf16x8*)wdp;
    // per-lane byte offsets into whext for (g, nh): frag (kt=0, nt=16g+2w+nh)
    int voff[4][2];
#pragma unroll
    for (int g = 0; g < 4; ++g)
#pragma unroll
        for (int nh = 0; nh < 2; ++nh)
            voff[g][nh] = ((16 * g + 2 * w + nh) * 64 + l) * 16;

    for (int step = 0; step < STEPS; ++step) {
        const u16* hr = hbuf + (step & 1) * HB;      // read buffer
        u16* hw = hbuf + ((step & 1) ^ 1) * HB;      // write buffer

        // kt=0 weight loads issued BEFORE the barrier; fly across it
        bf16x8 waA[4][2], waB[4][2];
#pragma unroll
        for (int g = 0; g < 4; ++g)
#pragma unroll
            for (int nh = 0; nh < 2; ++nh)
                waA[g][nh] = *(const bf16x8*)(wp + voff[g][nh]);

        sync_lds();   // hr (h + x_t + bias) ready; prior reads of hw done

        f32x4 acc[4][4][2];   // [bt][g][nh]
#pragma unroll
        for (int bt = 0; bt < 4; ++bt)
#pragma unroll
            for (int g = 0; g < 4; ++g)
#pragma unroll
                for (int nh = 0; nh < 2; ++nh) acc[bt][g][nh] = (f32x4){0.f, 0.f, 0.f, 0.f};

        bf16x8 hbA[4], hbB[4];
#pragma unroll
        for (int bt = 0; bt < 4; ++bt)
            hbA[bt] = *(const bf16x8*)&hr[(16 * bt + col) * PITCH + quad * 8];

        // A/B rotated pipeline; unroll 1 bounds live weight frags to 2 kt
#pragma unroll 1
        for (int kt = 0; kt < 8; kt += 2) {
            const char* wp1 = wp + (kt + 1) * 65536;
#pragma unroll
            for (int g = 0; g < 4; ++g)
#pragma unroll
                for (int nh = 0; nh < 2; ++nh)
                    waB[g][nh] = *(const bf16x8*)(wp1 + voff[g][nh]);
#pragma unroll
            for (int bt = 0; bt < 4; ++bt)
                hbB[bt] = *(const bf16x8*)&hr[(16 * bt + col) * PITCH + (kt + 1) * 32 + quad * 8];
            MFMA_BURST(waA, hbA);          // kt
            const char* wp2 = wp + (kt + 2) * 65536;
#pragma unroll
            for (int g = 0; g < 4; ++g)
#pragma unroll
                for (int nh = 0; nh < 2; ++nh)
                    waA[g][nh] = *(const bf16x8*)(wp2 + voff[g][nh]);
#pragma unroll
            for (int bt = 0; bt < 4; ++bt)
                hbA[bt] = *(const bf16x8*)&hr[(16 * bt + col) * PITCH + (kt + 2) * 32 + quad * 8];
            MFMA_BURST(waB, hbB);          // kt+1
        }
        MFMA_BURST(waA, hbA);              // kt=8 tail

        // gates; lane holds units u = 32w+16nh+4quad+r, batch m = 16bt+col
#pragma unroll
        for (int bt = 0; bt < 4; ++bt)
#pragma unroll
            for (int nh = 0; nh < 2; ++nh) {
                float* cp = &cbuf[(16 * bt + col) * CPITCH + 32 * w + 16 * nh + 4 * quad];
                f32x4 cold = *(const f32x4*)cp;
                f32x4 cnew;
                u16 hh[4];
#pragma unroll
                for (int r = 0; r < 4; ++r) {
                    float iv = sigm(acc[bt][0][nh][r]);
                    float fv = sigm(acc[bt][1][nh][r]);
                    float gv = tanh_f(acc[bt][2][nh][r]);
                    float ov = sigm(acc[bt][3][nh][r]);
                    float cn = fv * cold[r] + iv * gv;
                    cnew[r] = cn;
                    hh[r] = f2bf(ov * tanh_f(cn));
                }
                *(f32x4*)cp = cnew;
                *(ushort4*)&hw[(16 * bt + col) * PITCH + 32 * w + 16 * nh + 4 * quad] =
                    make_ushort4(hh[0], hh[1], hh[2], hh[3]);
            }

        if (step < WARM - 1) {
            if (w == 0) {   // x_{step+1} -> write buffer (read next step)
                const float4 xv = *(const float4*)(x + (rowBase + l) * 192 + (step + 1) * 4);
                u16* p = &hw[l * PITCH + 256];
                p[0] = f2bf(xv.x); p[1] = f2bf(xv.y); p[2] = f2bf(xv.z); p[3] = f2bf(xv.w);
            }
        } else {
            sync_lds();        // h_new in hw visible for pred GEMM
            if (w < 4) {       // pred^T = Wdext^T @ h_new^T ; wave w -> batch-tile w
                f32x4 pacc = (f32x4){0.f, 0.f, 0.f, 0.f};
#pragma unroll
                for (int kt = 0; kt < 9; ++kt) {
                    bf16x8 hbp = *(const bf16x8*)&hw[(16 * w + col) * PITCH + kt * 32 + quad * 8];
                    bf16x8 wap = dfrag[kt * 64 + l];
                    pacc = __builtin_amdgcn_mfma_f32_16x16x32_bf16(wap, hbp, pacc, 0, 0, 0);
                }
                if (quad == 0) {   // D rows 0..3 = the 4 features of batch 16w+col
                    int s = step - (WARM - 1);
                    *(float4*)&out[((rowBase + 16 * w + col) * 24 + s) * 4] =
                        make_float4(pacc[0], pacc[1], pacc[2], pacc[3]);
                    // feed back as next x_t
                    *(ushort4*)&hw[(16 * w + col) * PITCH + 256] =
                        make_ushort4(f2bf(pacc[0]), f2bf(pacc[1]), f2bf(pacc[2]), f2bf(pacc[3]));
                }
            }
        }
    }
}

extern "C" void kernel_launch(void* const* d_in, const int* in_sizes, int n_in,
                              void* d_out, int out_size, void* d_ws, size_t ws_size,
                              hipStream_t stream) {
    const float* x  = (const float*)d_in[0];   // [16384,48,4]
    const float* Wx = (const float*)d_in[1];   // [4,1024]
    const float* Wh = (const float*)d_in[2];   // [256,1024]
    const float* b  = (const float*)d_in[3];   // [1024]
    const float* Wd = (const float*)d_in[4];   // [256,4]
    const float* bd = (const float*)d_in[5];   // [4]
    float* out = (float*)d_out;                // [16384,24,4] fp32

    u16* whext = (u16*)d_ws;                        // 589824 B
    u16* wdp = (u16*)((char*)d_ws + 36864 * 16);    // 9216 B

    prep_weights<<<(36864 + 576 + 255) / 256, 256, 0, stream>>>(Wx, Wh, b, Wd, bd, whext, wdp);
    lstm_main<<<256, 512, 0, stream>>>(x, whext, wdp, out);
}

// Round 6
// 809.064 us; speedup vs baseline: 2.8586x; 1.0355x over previous
//
#include <hip/hip_runtime.h>

// LSTM feedback net: B=16384, T=48 warmup, F=4, UNITS=256, 24 AR steps.
// R6: rolling modulo-9 weight-stream pipeline. Weight addresses are
// step-invariant, so the kt stream is infinite and dependency-free:
//  - each wa refill issues a FULL iteration (~310 cyc) before its use
//    (R5 gave only ~155 cyc < L2 latency ~220 -> per-kt stall).
//  - the last refills of a step (waB<-tile1, waA<-tile0 of next step) issue
//    before the gate phase: ~2 kt of next step's stream hides under gate
//    VALU and crosses the LDS-only barrier in flight.
// Parity (9 tiles, odd): A consumes {0,2,4,6,8}, B {1,3,5,7} each step.
// Invariant from R1-R5: acc(128 AGPR) + pipeline regs must fit 256/wave at
// 2 waves/SIMD -> WRITE_SIZE ~1.1e4 KB is the no-spill signal.

typedef unsigned short u16;
typedef __attribute__((ext_vector_type(8))) short bf16x8;
typedef __attribute__((ext_vector_type(4))) float f32x4;

#define PITCH 296    // hext row pitch, elems (592 B/row)
#define HB 18944     // elems per h buffer (64*296)
#define CPITCH 264   // c row pitch, floats
#define WARM 48
#define STEPS 71     // 48 warmup + 23 AR cell steps

__device__ __forceinline__ u16 f2bf(float f) {
    unsigned u = __float_as_uint(f);
    u += 0x7FFFu + ((u >> 16) & 1u);   // round-to-nearest-even
    return (u16)(u >> 16);
}

__device__ __forceinline__ float sigm(float x) {
    return __builtin_amdgcn_rcpf(1.0f + __expf(-x));
}
// tanh(x) = 2*sigmoid(2x)-1 ; saturates correctly without NaN
__device__ __forceinline__ float tanh_f(float x) {
    return __builtin_amdgcn_rcpf(1.0f + __expf(-2.0f * x)) * 2.0f - 1.0f;
}

// LDS-only barrier: drain LDS ops, NOT vmcnt -> global loads stay in flight.
__device__ __forceinline__ void sync_lds() {
    asm volatile("s_waitcnt lgkmcnt(0)\n\ts_barrier" ::: "memory");
}

// ---- prep (unchanged): pack Whext (K=288 x N=1024) and Wdext into fragment
// blocks; lane l of block (kt,nt) holds W[kt*32+(l>>4)*8+j][nt*16+(l&15)].
// Fed as operand A: A[m=unit][k]. K rows: 0..255 Wh/Wd, 256..259 Wx, 260 bias.
__global__ void prep_weights(const float* __restrict__ Wx,
                             const float* __restrict__ Wh,
                             const float* __restrict__ b,
                             const float* __restrict__ Wd,
                             const float* __restrict__ bd,
                             u16* __restrict__ whext,
                             u16* __restrict__ wdp) {
    int idx = blockIdx.x * 256 + threadIdx.x;   // one thread per 16B chunk
    if (idx < 36864) {                          // 9 kt * 64 nt * 64 lanes
        int lane = idx & 63;
        int blk = idx >> 6;
        int nt = blk & 63;
        int kt = blk >> 6;
        int kbase = kt * 32 + (lane >> 4) * 8;
        int n = nt * 16 + (lane & 15);
        u16 v[8];
#pragma unroll
        for (int j = 0; j < 8; ++j) {
            int k = kbase + j;
            float f = 0.0f;
            if (k < 256) f = Wh[k * 1024 + n];
            else if (k < 260) f = Wx[(k - 256) * 1024 + n];
            else if (k == 260) f = b[n];
            v[j] = f2bf(f);
        }
        ushort4* dst = (ushort4*)(whext + (size_t)idx * 8);
        dst[0] = make_ushort4(v[0], v[1], v[2], v[3]);
        dst[1] = make_ushort4(v[4], v[5], v[6], v[7]);
    } else if (idx < 36864 + 576) {             // Wdext: 9 kt * 64 lanes
        int id2 = idx - 36864;
        int lane = id2 & 63;
        int kt = id2 >> 6;
        int kbase = kt * 32 + (lane >> 4) * 8;
        int n = lane & 15;
        u16 v[8];
#pragma unroll
        for (int j = 0; j < 8; ++j) {
            int k = kbase + j;
            float f = 0.0f;
            if (n < 4) {
                if (k < 256) f = Wd[k * 4 + n];
                else if (k == 260) f = bd[n];
            }
            v[j] = f2bf(f);
        }
        ushort4* dst = (ushort4*)(wdp + (size_t)id2 * 8);
        dst[0] = make_ushort4(v[0], v[1], v[2], v[3]);
        dst[1] = make_ushort4(v[4], v[5], v[6], v[7]);
    }
}

#define MFMA_BURST(WA, HBX)                                                   \
    _Pragma("unroll") for (int g = 0; g < 4; ++g)                             \
    _Pragma("unroll") for (int nh = 0; nh < 2; ++nh)                          \
    _Pragma("unroll") for (int bt = 0; bt < 4; ++bt)                          \
        acc[bt][g][nh] = __builtin_amdgcn_mfma_f32_16x16x32_bf16(             \
            WA[g][nh], HBX[bt], acc[bt][g][nh], 0, 0, 0);

#define WLOAD(DST, KTV) do {                                                  \
    const char* _wpk = wp + (size_t)(KTV) * 65536;                            \
    _Pragma("unroll") for (int g = 0; g < 4; ++g)                             \
    _Pragma("unroll") for (int nh = 0; nh < 2; ++nh)                          \
        DST[g][nh] = *(const bf16x8*)(_wpk + voff[g][nh]);                    \
} while (0)

#define HLOAD(DST, KTV) do {                                                  \
    _Pragma("unroll") for (int bt = 0; bt < 4; ++bt)                          \
        DST[bt] = *(const bf16x8*)&hr[(16 * bt + col) * PITCH + (KTV) * 32 + quad * 8]; \
} while (0)

__global__ __launch_bounds__(512, 2) void lstm_main(
    const float* __restrict__ x, const u16* __restrict__ whext,
    const u16* __restrict__ wdp, float* __restrict__ out) {
    __shared__ __align__(16) unsigned char smem[143360];
    u16* hbuf = (u16*)smem;                    // 2 x 18944 elems bf16 (75776 B)
    float* cbuf = (float*)(smem + 75776);      // c: [batch 64][unit, pitch 264] fp32

    const int tid = threadIdx.x;
    const int w = tid >> 6;        // wave 0..7 -> units [32w, 32w+32)
    const int l = tid & 63;
    const int col = l & 15;        // batch col within tile
    const int quad = l >> 4;
    const long long rowBase = (long long)blockIdx.x * 64;

    {   // zero all LDS (h buffers incl. pad cols, c)
        int4 z = make_int4(0, 0, 0, 0);
        for (int i = tid; i < 8960; i += 512) ((int4*)smem)[i] = z;
    }
    sync_lds();
    if (tid < 64) {
        hbuf[tid * PITCH + 260] = (u16)0x3F80;        // bias-1 col, buffer 0
        hbuf[HB + tid * PITCH + 260] = (u16)0x3F80;   // and buffer 1
        const float4 xv = *(const float4*)(x + (rowBase + tid) * 192);
        u16* p = &hbuf[tid * PITCH + 256];             // x_0 -> buffer 0
        p[0] = f2bf(xv.x); p[1] = f2bf(xv.y); p[2] = f2bf(xv.z); p[3] = f2bf(xv.w);
    }

    const char* __restrict__ wp = (const char*)whext;
    const bf16x8* __restrict__ dfrag = (const bf16x8*)wdp;
    // per-lane byte offsets into whext for (g, nh): frag (kt=0, nt=16g+2w+nh)
    int voff[4][2];
#pragma unroll
    for (int g = 0; g < 4; ++g)
#pragma unroll
        for (int nh = 0; nh < 2; ++nh)
            voff[g][nh] = ((16 * g + 2 * w + nh) * 64 + l) * 16;

    // rolling weight pipeline, persistent across steps
    bf16x8 waA[4][2], waB[4][2];
    WLOAD(waA, 0);
    WLOAD(waB, 1);

    for (int step = 0; step < STEPS; ++step) {
        const u16* hr = hbuf + (step & 1) * HB;      // read buffer
        u16* hw = hbuf + ((step & 1) ^ 1) * HB;      // write buffer

        sync_lds();   // hr (h + x_t + bias) ready; prior reads of hw done
                      // waA(0)/waB(1) issued pre-barrier are in flight

        f32x4 acc[4][4][2];   // [bt][g][nh]
#pragma unroll
        for (int bt = 0; bt < 4; ++bt)
#pragma unroll
            for (int g = 0; g < 4; ++g)
#pragma unroll
                for (int nh = 0; nh < 2; ++nh) acc[bt][g][nh] = (f32x4){0.f, 0.f, 0.f, 0.f};

        bf16x8 hbA[4], hbB[4];
        HLOAD(hbA, 0);
        HLOAD(hbB, 1);

        // A/B rotated pipeline; each refill issues one full iteration early
#pragma unroll 1
        for (int kt = 0; kt < 8; kt += 2) {
            MFMA_BURST(waA, hbA);          // consumes tile kt
            WLOAD(waA, kt + 2);            // {2,4,6,8}
            HLOAD(hbA, kt + 2);
            MFMA_BURST(waB, hbB);          // consumes tile kt+1
            {
                int kb = (kt == 6) ? 1 : kt + 3;   // {3,5,7, next-step 1}
                WLOAD(waB, kb);
            }
            if (kt < 6) HLOAD(hbB, kt + 3);
        }
        MFMA_BURST(waA, hbA);              // tile 8
        WLOAD(waA, 0);                     // next-step tile 0 -> hides under gates

        // gates; lane holds units u = 32w+16nh+4quad+r, batch m = 16bt+col
#pragma unroll
        for (int bt = 0; bt < 4; ++bt)
#pragma unroll
            for (int nh = 0; nh < 2; ++nh) {
                float* cp = &cbuf[(16 * bt + col) * CPITCH + 32 * w + 16 * nh + 4 * quad];
                f32x4 cold = *(const f32x4*)cp;
                f32x4 cnew;
                u16 hh[4];
#pragma unroll
                for (int r = 0; r < 4; ++r) {
                    float iv = sigm(acc[bt][0][nh][r]);
                    float fv = sigm(acc[bt][1][nh][r]);
                    float gv = tanh_f(acc[bt][2][nh][r]);
                    float ov = sigm(acc[bt][3][nh][r]);
                    float cn = fv * cold[r] + iv * gv;
                    cnew[r] = cn;
                    hh[r] = f2bf(ov * tanh_f(cn));
                }
                *(f32x4*)cp = cnew;
                *(ushort4*)&hw[(16 * bt + col) * PITCH + 32 * w + 16 * nh + 4 * quad] =
                    make_ushort4(hh[0], hh[1], hh[2], hh[3]);
            }

        if (step < WARM - 1) {
            if (w == 0) {   // x_{step+1} -> write buffer (read next step)
                const float4 xv = *(const float4*)(x + (rowBase + l) * 192 + (step + 1) * 4);
                u16* p = &hw[l * PITCH + 256];
                p[0] = f2bf(xv.x); p[1] = f2bf(xv.y); p[2] = f2bf(xv.z); p[3] = f2bf(xv.w);
            }
        } else {
            sync_lds();        // h_new in hw visible for pred GEMM
            if (w < 4) {       // pred^T = Wdext^T @ h_new^T ; wave w -> batch-tile w
                f32x4 pacc = (f32x4){0.f, 0.f, 0.f, 0.f};
#pragma unroll
                for (int kt = 0; kt < 9; ++kt) {
                    bf16x8 hbp = *(const bf16x8*)&hw[(16 * w + col) * PITCH + kt * 32 + quad * 8];
                    bf16x8 wap = dfrag[kt * 64 + l];
                    pacc = __builtin_amdgcn_mfma_f32_16x16x32_bf16(wap, hbp, pacc, 0, 0, 0);
                }
                if (quad == 0) {   // D rows 0..3 = the 4 features of batch 16w+col
                    int s = step - (WARM - 1);
                    *(float4*)&out[((rowBase + 16 * w + col) * 24 + s) * 4] =
                        make_float4(pacc[0], pacc[1], pacc[2], pacc[3]);
                    // feed back as next x_t
                    *(ushort4*)&hw[(16 * w + col) * PITCH + 256] =
                        make_ushort4(f2bf(pacc[0]), f2bf(pacc[1]), f2bf(pacc[2]), f2bf(pacc[3]));
                }
            }
        }
    }
}

extern "C" void kernel_launch(void* const* d_in, const int* in_sizes, int n_in,
                              void* d_out, int out_size, void* d_ws, size_t ws_size,
                              hipStream_t stream) {
    const float* x  = (const float*)d_in[0];   // [16384,48,4]
    const float* Wx = (const float*)d_in[1];   // [4,1024]
    const float* Wh = (const float*)d_in[2];   // [256,1024]
    const float* b  = (const float*)d_in[3];   // [1024]
    const float* Wd = (const float*)d_in[4];   // [256,4]
    const float* bd = (const float*)d_in[5];   // [4]
    float* out = (float*)d_out;                // [16384,24,4] fp32

    u16* whext = (u16*)d_ws;                        // 589824 B
    u16* wdp = (u16*)((char*)d_ws + 36864 * 16);    // 9216 B

    prep_weights<<<(36864 + 576 + 255) / 256, 256, 0, stream>>>(Wx, Wh, b, Wd, bd, whext, wdp);
    lstm_main<<<256, 512, 0, stream>>>(x, whext, wdp, out);
}

// Round 7
// 791.743 us; speedup vs baseline: 2.9211x; 1.0219x over previous
//
#include <hip/hip_runtime.h>

// LSTM feedback net: B=16384, T=48 warmup, F=4, UNITS=256, 24 AR steps.
// R7 = R6 structure + gate-VALU fix. Diagnosis: harness compiles without
// -ffast-math, so __expf() lowered to precise OCML exp (~15-20 instr) ->
// gates consumed ~53% VALUBusy. Fix: raw v_exp_f32 via
// __builtin_amdgcn_exp2f, with log2(e) folded into the packed weights
// (i,f,o columns x1.4427, g columns x2.8854 -> tanh via scaled sigmoid).
// Only tanh(c_new) needs a runtime scale multiply.

typedef unsigned short u16;
typedef __attribute__((ext_vector_type(8))) short bf16x8;
typedef __attribute__((ext_vector_type(4))) float f32x4;

#define PITCH 296    // hext row pitch, elems (592 B/row)
#define HB 18944     // elems per h buffer (64*296)
#define CPITCH 264   // c row pitch, floats
#define WARM 48
#define STEPS 71     // 48 warmup + 23 AR cell steps
#define LOG2E  1.442695041f
#define LOG2E2 2.885390082f

__device__ __forceinline__ u16 f2bf(float f) {
    unsigned u = __float_as_uint(f);
    u += 0x7FFFu + ((u >> 16) & 1u);   // round-to-nearest-even
    return (u16)(u >> 16);
}

// sigmoid of a pre-scaled logit: expects zp = z * log2(e)
__device__ __forceinline__ float sigm2(float zp) {
    return __builtin_amdgcn_rcpf(1.0f + __builtin_amdgcn_exp2f(-zp));
}

// LDS-only barrier: drain LDS ops, NOT vmcnt -> global loads stay in flight.
__device__ __forceinline__ void sync_lds() {
    asm volatile("s_waitcnt lgkmcnt(0)\n\ts_barrier" ::: "memory");
}

// ---- prep: pack Whext (K=288 x N=1024) and Wdext into fragment blocks;
// lane l of block (kt,nt) holds W[kt*32+(l>>4)*8+j][nt*16+(l&15)].
// K rows: 0..255 Wh/Wd, 256..259 Wx, 260 bias.
// NEW: columns pre-scaled by log2e (gates i,f,o) / 2*log2e (gate g) so the
// main kernel's sigmoids use raw exp2. Wd/bd (linear output) unscaled.
__global__ void prep_weights(const float* __restrict__ Wx,
                             const float* __restrict__ Wh,
                             const float* __restrict__ b,
                             const float* __restrict__ Wd,
                             const float* __restrict__ bd,
                             u16* __restrict__ whext,
                             u16* __restrict__ wdp) {
    int idx = blockIdx.x * 256 + threadIdx.x;   // one thread per 16B chunk
    if (idx < 36864) {                          // 9 kt * 64 nt * 64 lanes
        int lane = idx & 63;
        int blk = idx >> 6;
        int nt = blk & 63;
        int kt = blk >> 6;
        int kbase = kt * 32 + (lane >> 4) * 8;
        int n = nt * 16 + (lane & 15);
        float sc = (n >= 512 && n < 768) ? LOG2E2 : LOG2E;   // g-gate cols x2
        u16 v[8];
#pragma unroll
        for (int j = 0; j < 8; ++j) {
            int k = kbase + j;
            float f = 0.0f;
            if (k < 256) f = Wh[k * 1024 + n];
            else if (k < 260) f = Wx[(k - 256) * 1024 + n];
            else if (k == 260) f = b[n];
            v[j] = f2bf(f * sc);
        }
        ushort4* dst = (ushort4*)(whext + (size_t)idx * 8);
        dst[0] = make_ushort4(v[0], v[1], v[2], v[3]);
        dst[1] = make_ushort4(v[4], v[5], v[6], v[7]);
    } else if (idx < 36864 + 576) {             // Wdext: 9 kt * 64 lanes
        int id2 = idx - 36864;
        int lane = id2 & 63;
        int kt = id2 >> 6;
        int kbase = kt * 32 + (lane >> 4) * 8;
        int n = lane & 15;
        u16 v[8];
#pragma unroll
        for (int j = 0; j < 8; ++j) {
            int k = kbase + j;
            float f = 0.0f;
            if (n < 4) {
                if (k < 256) f = Wd[k * 4 + n];
                else if (k == 260) f = bd[n];
            }
            v[j] = f2bf(f);
        }
        ushort4* dst = (ushort4*)(wdp + (size_t)id2 * 8);
        dst[0] = make_ushort4(v[0], v[1], v[2], v[3]);
        dst[1] = make_ushort4(v[4], v[5], v[6], v[7]);
    }
}

#define MFMA_BURST(WA, HBX)                                                   \
    _Pragma("unroll") for (int g = 0; g < 4; ++g)                             \
    _Pragma("unroll") for (int nh = 0; nh < 2; ++nh)                          \
    _Pragma("unroll") for (int bt = 0; bt < 4; ++bt)                          \
        acc[bt][g][nh] = __builtin_amdgcn_mfma_f32_16x16x32_bf16(             \
            WA[g][nh], HBX[bt], acc[bt][g][nh], 0, 0, 0);

#define WLOAD(DST, KTV) do {                                                  \
    const char* _wpk = wp + (size_t)(KTV) * 65536;                            \
    _Pragma("unroll") for (int g = 0; g < 4; ++g)                             \
    _Pragma("unroll") for (int nh = 0; nh < 2; ++nh)                          \
        DST[g][nh] = *(const bf16x8*)(_wpk + voff[g][nh]);                    \
} while (0)

#define HLOAD(DST, KTV) do {                                                  \
    _Pragma("unroll") for (int bt = 0; bt < 4; ++bt)                          \
        DST[bt] = *(const bf16x8*)&hr[(16 * bt + col) * PITCH + (KTV) * 32 + quad * 8]; \
} while (0)

__global__ __launch_bounds__(512, 2) void lstm_main(
    const float* __restrict__ x, const u16* __restrict__ whext,
    const u16* __restrict__ wdp, float* __restrict__ out) {
    __shared__ __align__(16) unsigned char smem[143360];
    u16* hbuf = (u16*)smem;                    // 2 x 18944 elems bf16 (75776 B)
    float* cbuf = (float*)(smem + 75776);      // c: [batch 64][unit, pitch 264] fp32

    const int tid = threadIdx.x;
    const int w = tid >> 6;        // wave 0..7 -> units [32w, 32w+32)
    const int l = tid & 63;
    const int col = l & 15;        // batch col within tile
    const int quad = l >> 4;
    const long long rowBase = (long long)blockIdx.x * 64;

    {   // zero all LDS (h buffers incl. pad cols, c)
        int4 z = make_int4(0, 0, 0, 0);
        for (int i = tid; i < 8960; i += 512) ((int4*)smem)[i] = z;
    }
    sync_lds();
    if (tid < 64) {
        hbuf[tid * PITCH + 260] = (u16)0x3F80;        // bias-1 col, buffer 0
        hbuf[HB + tid * PITCH + 260] = (u16)0x3F80;   // and buffer 1
        const float4 xv = *(const float4*)(x + (rowBase + tid) * 192);
        u16* p = &hbuf[tid * PITCH + 256];             // x_0 -> buffer 0
        p[0] = f2bf(xv.x); p[1] = f2bf(xv.y); p[2] = f2bf(xv.z); p[3] = f2bf(xv.w);
    }

    const char* __restrict__ wp = (const char*)whext;
    const bf16x8* __restrict__ dfrag = (const bf16x8*)wdp;
    // per-lane byte offsets into whext for (g, nh): frag (kt=0, nt=16g+2w+nh)
    int voff[4][2];
#pragma unroll
    for (int g = 0; g < 4; ++g)
#pragma unroll
        for (int nh = 0; nh < 2; ++nh)
            voff[g][nh] = ((16 * g + 2 * w + nh) * 64 + l) * 16;

    // rolling weight pipeline, persistent across steps
    bf16x8 waA[4][2], waB[4][2];
    WLOAD(waA, 0);
    WLOAD(waB, 1);

    for (int step = 0; step < STEPS; ++step) {
        const u16* hr = hbuf + (step & 1) * HB;      // read buffer
        u16* hw = hbuf + ((step & 1) ^ 1) * HB;      // write buffer

        sync_lds();   // hr (h + x_t + bias) ready; prior reads of hw done
                      // waA(0)/waB(1) issued pre-barrier are in flight

        f32x4 acc[4][4][2];   // [bt][g][nh]
#pragma unroll
        for (int bt = 0; bt < 4; ++bt)
#pragma unroll
            for (int g = 0; g < 4; ++g)
#pragma unroll
                for (int nh = 0; nh < 2; ++nh) acc[bt][g][nh] = (f32x4){0.f, 0.f, 0.f, 0.f};

        bf16x8 hbA[4], hbB[4];
        HLOAD(hbA, 0);
        HLOAD(hbB, 1);

        // A/B rotated pipeline; each refill issues one full iteration early
#pragma unroll 1
        for (int kt = 0; kt < 8; kt += 2) {
            MFMA_BURST(waA, hbA);          // consumes tile kt
            WLOAD(waA, kt + 2);            // {2,4,6,8}
            HLOAD(hbA, kt + 2);
            MFMA_BURST(waB, hbB);          // consumes tile kt+1
            {
                int kb = (kt == 6) ? 1 : kt + 3;   // {3,5,7, next-step 1}
                WLOAD(waB, kb);
            }
            if (kt < 6) HLOAD(hbB, kt + 3);
        }
        MFMA_BURST(waA, hbA);              // tile 8
        WLOAD(waA, 0);                     // next-step tile 0 -> hides under gates

        // gates; lane holds units u = 32w+16nh+4quad+r, batch m = 16bt+col
        // z pre-scaled by log2e (i,f,o) / 2*log2e (g) via weight packing.
#pragma unroll
        for (int bt = 0; bt < 4; ++bt)
#pragma unroll
            for (int nh = 0; nh < 2; ++nh) {
                float* cp = &cbuf[(16 * bt + col) * CPITCH + 32 * w + 16 * nh + 4 * quad];
                f32x4 cold = *(const f32x4*)cp;
                f32x4 cnew;
                u16 hh[4];
#pragma unroll
                for (int r = 0; r < 4; ++r) {
                    float iv = sigm2(acc[bt][0][nh][r]);
                    float fv = sigm2(acc[bt][1][nh][r]);
                    float gv = 2.0f * sigm2(acc[bt][2][nh][r]) - 1.0f;   // tanh
                    float ov = sigm2(acc[bt][3][nh][r]);
                    float cn = fv * cold[r] + iv * gv;
                    cnew[r] = cn;
                    float ts = sigm2(LOG2E2 * cn);                       // tanh(cn)
                    hh[r] = f2bf(ov * (2.0f * ts - 1.0f));
                }
                *(f32x4*)cp = cnew;
                *(ushort4*)&hw[(16 * bt + col) * PITCH + 32 * w + 16 * nh + 4 * quad] =
                    make_ushort4(hh[0], hh[1], hh[2], hh[3]);
            }

        if (step < WARM - 1) {
            if (w == 0) {   // x_{step+1} -> write buffer (read next step)
                const float4 xv = *(const float4*)(x + (rowBase + l) * 192 + (step + 1) * 4);
                u16* p = &hw[l * PITCH + 256];
                p[0] = f2bf(xv.x); p[1] = f2bf(xv.y); p[2] = f2bf(xv.z); p[3] = f2bf(xv.w);
            }
        } else {
            sync_lds();        // h_new in hw visible for pred GEMM
            if (w < 4) {       // pred^T = Wdext^T @ h_new^T ; wave w -> batch-tile w
                f32x4 pacc = (f32x4){0.f, 0.f, 0.f, 0.f};
#pragma unroll
                for (int kt = 0; kt < 9; ++kt) {
                    bf16x8 hbp = *(const bf16x8*)&hw[(16 * w + col) * PITCH + kt * 32 + quad * 8];
                    bf16x8 wap = dfrag[kt * 64 + l];
                    pacc = __builtin_amdgcn_mfma_f32_16x16x32_bf16(wap, hbp, pacc, 0, 0, 0);
                }
                if (quad == 0) {   // D rows 0..3 = the 4 features of batch 16w+col
                    int s = step - (WARM - 1);
                    *(float4*)&out[((rowBase + 16 * w + col) * 24 + s) * 4] =
                        make_float4(pacc[0], pacc[1], pacc[2], pacc[3]);
                    // feed back as next x_t
                    *(ushort4*)&hw[(16 * w + col) * PITCH + 256] =
                        make_ushort4(f2bf(pacc[0]), f2bf(pacc[1]), f2bf(pacc[2]), f2bf(pacc[3]));
                }
            }
        }
    }
}

extern "C" void kernel_launch(void* const* d_in, const int* in_sizes, int n_in,
                              void* d_out, int out_size, void* d_ws, size_t ws_size,
                              hipStream_t stream) {
    const float* x  = (const float*)d_in[0];   // [16384,48,4]
    const float* Wx = (const float*)d_in[1];   // [4,1024]
    const float* Wh = (const float*)d_in[2];   // [256,1024]
    const float* b  = (const float*)d_in[3];   // [1024]
    const float* Wd = (const float*)d_in[4];   // [256,4]
    const float* bd = (const float*)d_in[5];   // [4]
    float* out = (float*)d_out;                // [16384,24,4] fp32

    u16* whext = (u16*)d_ws;                        // 589824 B
    u16* wdp = (u16*)((char*)d_ws + 36864 * 16);    // 9216 B

    prep_weights<<<(36864 + 576 + 255) / 256, 256, 0, stream>>>(Wx, Wh, b, Wd, bd, whext, wdp);
    lstm_main<<<256, 512, 0, stream>>>(x, whext, wdp, out);
}